// Round 8
// baseline (556.483 us; speedup 1.0000x reference)
//
#include <hip/hip_runtime.h>

#define N_USERS 100000
#define N_ITEMS 200000
#define N_NODES (N_USERS + N_ITEMS)
#define EMB     64
#define NNZ     4000000

// coarse row-buckets: 512 rows each (r8: was 1024 -> place was 1 block/CU
// with a 2x imbalance tail; 512-row buckets give 2 blocks/CU, 586 blocks)
#define BSHIFT 9
#define BROWS  (1 << BSHIFT)                               // 512 rows / bucket
#define NBUCK  ((N_NODES + BROWS - 1) >> BSHIFT)           // 586
#define NB2    1024                                        // padded scan slots

// block-aggregated binning pass
#define AGG_THR    512
#define AGG_EPT    8
#define AGG_T      (AGG_THR * AGG_EPT)                     // 4096 edges / block
#define AGG_BLOCKS ((NNZ + AGG_T - 1) / AGG_T)             // 977

// bucket segment capacity (mean fill 6826, sigma ~83 -> +16.5 sigma headroom)
#define SEGCAP 8192
#define PITER  (SEGCAP / 512)                              // 16

typedef _Float16 h4 __attribute__((ext_vector_type(4)));   // 8B vector of fp16

// NOTE (r3): __builtin_nontemporal_load on gfx950 = last-use/invalidating;
// on dirty lines -> ~35x WRITE amplification. Plain loads only.
// NOTE (r4): per-edge global atomics cost ~32B HBM each. Aggregate in LDS.
// NOTE (r6): gather is DRAM/L2-miss-path bound; only byte reduction helps.
// NOTE (r7): fp16 gather sources halve bytes, absmax unchanged (1.5e-5).

__device__ __forceinline__ int wave_incl_scan(int v, int lane) {
#pragma unroll
    for (int d = 1; d < 64; d <<= 1) {
        int t = __shfl_up(v, d, 64);
        if (lane >= d) v += t;
    }
    return v;
}

// ===========================================================================
// CSR build (histogram-free, bucket-segmented)
// ===========================================================================
// pass 1: bin 4096 edges/block into coarse buckets via LDS counting-sort;
// one global atomic per (block,bucket); coalesced segment writes.
// pk = b(10b)<<21 | rlo(9b)<<12 | lp(12b). pay.x packs col(19b) | rlo<<19.
__global__ __launch_bounds__(AGG_THR)
void bucket_agg_kernel(const int*   __restrict__ rows,
                       const int*   __restrict__ cols,
                       const float* __restrict__ vals,
                       int*         __restrict__ bcnt,   // [NBUCK*16] zeroed
                       float2*      __restrict__ pay) {  // [NBUCK*SEGCAP]
    __shared__ int            cntS[NB2];      // counts -> excl scan (4KB)
    __shared__ int            hoff[NB2];      // segment offset per bucket
    __shared__ int            waveTotS[8];
    __shared__ float2         payS[AGG_T];    // staged (packed col, val) 32KB
    __shared__ unsigned short bidS[AGG_T];    // bucket id per staged slot 8KB

    int tid  = threadIdx.x;
    int lane = tid & 63;
    int wid  = tid >> 6;
    int base = blockIdx.x * AGG_T;

    cntS[tid]       = 0;
    cntS[tid + 512] = 0;
    __syncthreads();

    // phase A: count
    unsigned pk[AGG_EPT];
#pragma unroll
    for (int j = 0; j < AGG_EPT; j++) {
        int e = base + j * AGG_THR + tid;
        pk[j] = 0xFFFFFFFFu;
        if (e < NNZ) {
            int r  = rows[e];
            int b  = r >> BSHIFT;                    // 10 bits
            int lp = atomicAdd(&cntS[b], 1);         // <= 4095, 12 bits
            pk[j]  = ((unsigned)b << 21) | ((unsigned)(r & (BROWS - 1)) << 12)
                   | (unsigned)lp;
        }
    }
    __syncthreads();

    // blocked exclusive scan of cntS[0..1023] (2 slots per thread) via shfl
    int v0 = cntS[2 * tid];
    int v1 = cntS[2 * tid + 1];
    int pv = v0 + v1;
    int incl = wave_incl_scan(pv, lane);
    if (lane == 63) waveTotS[wid] = incl;
    __syncthreads();
    int wbase = 0;
    for (int w = 0; w < wid; w++) wbase += waveTotS[w];
    int excl0 = wbase + incl - pv;
    int excl1 = excl0 + v0;

    // reserve segment runs (one atomic per non-empty bucket)
    if (2 * tid     < NBUCK && v0 > 0) hoff[2 * tid    ] = atomicAdd(&bcnt[(2 * tid    ) * 16], v0);
    if (2 * tid + 1 < NBUCK && v1 > 0) hoff[2 * tid + 1] = atomicAdd(&bcnt[(2 * tid + 1) * 16], v1);
    cntS[2 * tid]     = excl0;
    cntS[2 * tid + 1] = excl1;
    __syncthreads();

    // phase B: stage into LDS at counting-sort position
#pragma unroll
    for (int j = 0; j < AGG_EPT; j++) {
        if (pk[j] != 0xFFFFFFFFu) {
            int e   = base + j * AGG_THR + tid;
            int b   = pk[j] >> 21;
            int rl  = (pk[j] >> 12) & (BROWS - 1);
            int lp  = pk[j] & 0xFFF;
            int idx = cntS[b] + lp;
            unsigned packed = (unsigned)cols[e] | ((unsigned)rl << 19);
            payS[idx] = make_float2(__uint_as_float(packed), vals[e]);
            bidS[idx] = (unsigned short)b;
        }
    }
    __syncthreads();

    // write-out: contiguous per-bucket runs into fixed segments
    int total = NNZ - base; if (total > AGG_T) total = AGG_T;
    for (int i = tid; i < total; i += AGG_THR) {
        int b   = bidS[i];
        int pos = hoff[b] + (i - cntS[b]);
        if (pos < SEGCAP)   // 16-sigma safety clamp
            pay[(size_t)b * SEGCAP + pos] = payS[i];
    }
}

// tiny pass: exclusive-scan the 586 bucket totals -> bbase; seal row_ptr end.
__global__ void bscan_kernel(const int* __restrict__ bcnt,
                             int* __restrict__ bbase,
                             int* __restrict__ row_ptr) {
    __shared__ int s[1024];
    int tid = threadIdx.x;
    int v = 0;
    if (tid < NBUCK) {
        v = bcnt[tid * 16];
        if (v > SEGCAP) v = SEGCAP;
    }
    s[tid] = v;
    __syncthreads();
    for (int off = 1; off < 1024; off <<= 1) {
        int t = 0;
        if (tid >= off) t = s[tid - off];
        __syncthreads();
        if (tid >= off) s[tid] += t;
        __syncthreads();
    }
    if (tid < NBUCK) bbase[tid] = s[tid] - v;
    if (tid == 1023) bbase[NBUCK] = s[1023];
    if (tid == 0)    row_ptr[N_NODES] = NNZ;
}

// pass 2: one block per 512-row bucket (2 blocks/CU). Counting-sort the
// bucket's segment by row IN LDS, emit row_ptr slice, stream sorted run out
// coalesced. Also converts this bucket's rows to the fp16 shadow eh
// (replaces the separate initH pass).
__global__ __launch_bounds__(512)
void place_kernel(const int*    __restrict__ bcnt,
                  const int*    __restrict__ bbase,
                  const float2* __restrict__ pay,
                  int*          __restrict__ row_ptr,
                  float2*       __restrict__ edges,
                  const float*  __restrict__ user_t,
                  const float*  __restrict__ item_t,
                  _Float16*     __restrict__ eh) {
    __shared__ float2 payS[SEGCAP];   // 65536 B
    __shared__ int    cntS[BROWS];    //  2048 B
    __shared__ int    waveTotS[8];
    int b    = blockIdx.x;
    int tid  = threadIdx.x;
    int lane = tid & 63;
    int wid  = tid >> 6;
    int run  = bcnt[b * 16]; if (run > SEGCAP) run = SEGCAP;
    int beg  = bbase[b];
    const float2* seg = pay + (size_t)b * SEGCAP;

    cntS[tid] = 0;
    __syncthreads();

    // phase A: pull edges into registers, histogram rows (atomic ret = slot)
    unsigned eu[PITER]; float ev[PITER]; int elp[PITER];
#pragma unroll
    for (int j = 0; j < PITER; j++) {
        int i = j * 512 + tid;
        eu[j] = 0xFFFFFFFFu;
        if (i < run) {
            float2 p = seg[i];
            unsigned u = __float_as_uint(p.x);
            eu[j] = u;
            ev[j] = p.y;
            elp[j] = atomicAdd(&cntS[(u >> 19) & (BROWS - 1)], 1);
        }
    }
    __syncthreads();

    // inclusive scan of 512 row-counts via shfl
    int v = cntS[tid];
    int incl = wave_incl_scan(v, lane);
    if (lane == 63) waveTotS[wid] = incl;
    __syncthreads();
    int wbase = 0;
    for (int w = 0; w < wid; w++) wbase += waveTotS[w];
    incl += wbase;
    cntS[tid] = incl;   // inclusive; exclusive(r) = cntS[r-1]

    // emit row_ptr slice (coalesced)
    int gr = (b << BSHIFT) + tid;
    if (gr < N_NODES) row_ptr[gr] = beg + incl - v;
    __syncthreads();

    // phase B: scatter into LDS at final sorted position
#pragma unroll
    for (int j = 0; j < PITER; j++) {
        if (eu[j] != 0xFFFFFFFFu) {
            int r    = (int)((eu[j] >> 19) & (BROWS - 1));
            int base = (r == 0) ? 0 : cntS[r - 1];
            payS[base + elp[j]] = make_float2(__uint_as_float(eu[j] & 0x7FFFFu), ev[j]);
        }
    }
    __syncthreads();

    // phase C: stream out sequentially — full-line coalesced stores
    for (int i = tid; i < run; i += 512) {
        edges[beg + i] = payS[i];
    }

    // phase D: build fp16 shadow for this bucket's rows (coalesced stream)
    int r0   = b << BSHIFT;
    int nrow = N_NODES - r0; if (nrow > BROWS) nrow = BROWS;
    if (nrow > 0) {
        int nel = nrow << 6;
        for (int i = tid; i < nel; i += 512) {
            int gr2 = r0 + (i >> 6);
            int d   = i & 63;
            float x = (gr2 < N_USERS)
                    ? user_t[(size_t)gr2 * EMB + d]
                    : item_t[(size_t)(gr2 - N_USERS) * EMB + d];
            eh[(size_t)r0 * EMB + i] = (_Float16)x;
        }
    }
}

// ===========================================================================
// SpMM core: fp16 gather source (128B/row), fp32 accumulate.
// ===========================================================================
__device__ __forceinline__ float4 row_gather_h(const int*      __restrict__ rp,
                                               const float2*   __restrict__ edges,
                                               const _Float16* __restrict__ xh,
                                               int row, int s) {
    int i   = rp[row];
    int end = rp[row + 1];
    float4 acc = make_float4(0.f, 0.f, 0.f, 0.f);
    for (; i + 3 < end; i += 4) {
        float2 e0 = edges[i];
        float2 e1 = edges[i + 1];
        float2 e2 = edges[i + 2];
        float2 e3 = edges[i + 3];
        h4 a = *(const h4*)(xh + ((size_t)__float_as_int(e0.x) << 6) + (s << 2));
        h4 b = *(const h4*)(xh + ((size_t)__float_as_int(e1.x) << 6) + (s << 2));
        h4 c = *(const h4*)(xh + ((size_t)__float_as_int(e2.x) << 6) + (s << 2));
        h4 d = *(const h4*)(xh + ((size_t)__float_as_int(e3.x) << 6) + (s << 2));
        acc.x += e0.y * (float)a.x + e1.y * (float)b.x + e2.y * (float)c.x + e3.y * (float)d.x;
        acc.y += e0.y * (float)a.y + e1.y * (float)b.y + e2.y * (float)c.y + e3.y * (float)d.y;
        acc.z += e0.y * (float)a.z + e1.y * (float)b.z + e2.y * (float)c.z + e3.y * (float)d.z;
        acc.w += e0.y * (float)a.w + e1.y * (float)b.w + e2.y * (float)c.w + e3.y * (float)d.w;
    }
    for (; i < end; ++i) {
        float2 e0 = edges[i];
        h4 a = *(const h4*)(xh + ((size_t)__float_as_int(e0.x) << 6) + (s << 2));
        acc.x += e0.y * (float)a.x;
        acc.y += e0.y * (float)a.y;
        acc.z += e0.y * (float)a.z;
        acc.w += e0.y * (float)a.w;
    }
    return acc;
}

// layers 1,2: y_h = fp16(A * x_h)
__global__ void spmm_yh_kernel(const int*      __restrict__ rp,
                               const float2*   __restrict__ edges,
                               const _Float16* __restrict__ xh,
                               _Float16*       __restrict__ yh) {
    int t    = blockIdx.x * blockDim.x + threadIdx.x;
    int wid  = t >> 6;
    int lane = t & 63;
    int q    = lane >> 4;
    int s    = lane & 15;
    int row  = (wid << 2) + q;
    if (row >= N_NODES) return;
    float4 acc = row_gather_h(rp, edges, xh, row, s);
    h4 h = { (_Float16)acc.x, (_Float16)acc.y, (_Float16)acc.z, (_Float16)acc.w };
    *(h4*)(yh + (((size_t)row << 6) + (s << 2))) = h;
}

// layer 3 fused final: out = (e_fp32 + y1 + y2 + A*y2) / 4
__global__ void spmm_fin_kernel(const int*      __restrict__ rp,
                                const float2*   __restrict__ edges,
                                const float*    __restrict__ user_t,
                                const float*    __restrict__ item_t,
                                const _Float16* __restrict__ y1h,
                                const _Float16* __restrict__ y2h,
                                float*          __restrict__ out) {
    int t    = blockIdx.x * blockDim.x + threadIdx.x;
    int wid  = t >> 6;
    int lane = t & 63;
    int q    = lane >> 4;
    int s    = lane & 15;
    int row  = (wid << 2) + q;
    if (row >= N_NODES) return;
    float4 acc = row_gather_h(rp, edges, y2h, row, s);
    size_t o = ((size_t)row << 6) + (s << 2);
    float4 ev;
    if (row < N_USERS)
        ev = *(const float4*)(user_t + o);
    else
        ev = *(const float4*)(item_t + o - ((size_t)N_USERS << 6));
    h4 v1 = *(const h4*)(y1h + o);
    h4 v2 = *(const h4*)(y2h + o);
    float4 r;
    r.x = (ev.x + (float)v1.x + (float)v2.x + acc.x) * 0.25f;
    r.y = (ev.y + (float)v1.y + (float)v2.y + acc.y) * 0.25f;
    r.z = (ev.z + (float)v1.z + (float)v2.z + acc.z) * 0.25f;
    r.w = (ev.w + (float)v1.w + (float)v2.w + acc.w) * 0.25f;
    *(float4*)(out + o) = r;
}

// ===========================================================================
// Fallback atomic path (tiny ws only)
// ===========================================================================
__global__ void init_kernel(const float* __restrict__ user_t,
                            const float* __restrict__ item_t,
                            float* __restrict__ out,
                            float* __restrict__ bufA,
                            float* __restrict__ bufB) {
    int i = blockIdx.x * blockDim.x + threadIdx.x;
    const int total4 = N_NODES * EMB / 4;
    if (i >= total4) return;
    int fi   = i * 4;
    int node = fi >> 6;
    int off  = fi & 63;
    float4 v;
    if (node < N_USERS)
        v = *(const float4*)(user_t + (size_t)node * EMB + off);
    else
        v = *(const float4*)(item_t + (size_t)(node - N_USERS) * EMB + off);
    *(float4*)(out  + fi) = v;
    *(float4*)(bufA + fi) = v;
    *(float4*)(bufB + fi) = make_float4(0.f, 0.f, 0.f, 0.f);
}

__global__ void spmm_kernel(const int*   __restrict__ rows,
                            const int*   __restrict__ cols,
                            const float* __restrict__ vals,
                            const float* __restrict__ x,
                            float*       __restrict__ y) {
    int tid  = blockIdx.x * blockDim.x + threadIdx.x;
    int e    = tid >> 6;
    int lane = tid & 63;
    if (e >= NNZ) return;
    atomicAdd(&y[(size_t)rows[e] * EMB + lane], vals[e] * x[(size_t)cols[e] * EMB + lane]);
}

__global__ void acc_zero_kernel(float* __restrict__ out,
                                const float* __restrict__ src,
                                float* __restrict__ zbuf) {
    int i = blockIdx.x * blockDim.x + threadIdx.x;
    const int total4 = N_NODES * EMB / 4;
    if (i >= total4) return;
    int fi = i * 4;
    float4 o = *(float4*)(out + fi);
    float4 s = *(const float4*)(src + fi);
    o.x += s.x; o.y += s.y; o.z += s.z; o.w += s.w;
    *(float4*)(out  + fi) = o;
    *(float4*)(zbuf + fi) = make_float4(0.f, 0.f, 0.f, 0.f);
}

__global__ void final_kernel(float* __restrict__ out,
                             const float* __restrict__ src) {
    int i = blockIdx.x * blockDim.x + threadIdx.x;
    const int total4 = N_NODES * EMB / 4;
    if (i >= total4) return;
    int fi = i * 4;
    float4 o = *(float4*)(out + fi);
    float4 s = *(const float4*)(src + fi);
    o.x = (o.x + s.x) * 0.25f;
    o.y = (o.y + s.y) * 0.25f;
    o.z = (o.z + s.z) * 0.25f;
    o.w = (o.w + s.w) * 0.25f;
    *(float4*)(out + fi) = o;
}

// ===========================================================================
extern "C" void kernel_launch(void* const* d_in, const int* in_sizes, int n_in,
                              void* d_out, int out_size, void* d_ws, size_t ws_size,
                              hipStream_t stream) {
    const float* user_t = (const float*)d_in[0];
    const float* item_t = (const float*)d_in[1];
    const int*   rows   = (const int*)d_in[2];
    const int*   cols   = (const int*)d_in[3];
    const float* vals   = (const float*)d_in[4];
    float* out = (float*)d_out;

    const size_t embh_bytes  = (size_t)N_NODES * EMB * 2;         // 38.4 MB
    const size_t emb_bytes   = (size_t)N_NODES * EMB * 4;         // 76.8 MB
    const size_t pay_bytes   = (size_t)NBUCK * SEGCAP * 8;        // 38.4 MB
    const size_t edges_bytes = (size_t)NNZ * 8;                   // 32 MB
    const size_t small_bytes = (size_t)(N_NODES + 1) * 4
                             + (size_t)NBUCK * 16 * 4
                             + (size_t)(NBUCK + 1) * 4;
    const int total4    = N_NODES * EMB / 4;
    const int ew_blocks = (total4 + 255) / 256;

    const size_t need_h = pay_bytes + 3 * embh_bytes + edges_bytes + small_bytes; // ~187 MB
    const int spmm_blocks = (int)(((size_t)N_NODES / 4 * 64 + 255) / 256); // 18750

    if (ws_size >= need_h) {
        // ---- fp16-gather tier ----
        char* p = (char*)d_ws;
        float2*   pay     = (float2*)p;   p += pay_bytes;
        _Float16* eh      = (_Float16*)p; p += embh_bytes;
        _Float16* y1h     = (_Float16*)p; p += embh_bytes;
        _Float16* y2h     = (_Float16*)p; p += embh_bytes;
        float2*   edges   = (float2*)p;   p += edges_bytes;
        int*      row_ptr = (int*)p;      p += (size_t)(N_NODES + 1) * 4;
        int*      bcnt    = (int*)p;      p += (size_t)NBUCK * 16 * 4;
        int*      bbase   = (int*)p;

        hipMemsetAsync(bcnt, 0, (size_t)NBUCK * 16 * 4, stream);
        bucket_agg_kernel<<<AGG_BLOCKS, AGG_THR, 0, stream>>>(rows, cols, vals, bcnt, pay);
        bscan_kernel<<<1, 1024, 0, stream>>>(bcnt, bbase, row_ptr);
        place_kernel<<<NBUCK, 512, 0, stream>>>(bcnt, bbase, pay, row_ptr, edges,
                                                user_t, item_t, eh);

        spmm_yh_kernel <<<spmm_blocks, 256, 0, stream>>>(row_ptr, edges, eh,  y1h);
        spmm_yh_kernel <<<spmm_blocks, 256, 0, stream>>>(row_ptr, edges, y1h, y2h);
        spmm_fin_kernel<<<spmm_blocks, 256, 0, stream>>>(row_ptr, edges, user_t, item_t,
                                                         y1h, y2h, out);
    } else {
        // ---- tiny-ws fallback ----
        char* p = (char*)d_ws;
        float* bufA = (float*)p; p += emb_bytes;
        float* bufB = (float*)p;
        const int spmmA_blocks = (int)(((size_t)NNZ * 64 + 255) / 256);
        init_kernel<<<ew_blocks, 256, 0, stream>>>(user_t, item_t, out, bufA, bufB);
        spmm_kernel<<<spmmA_blocks, 256, 0, stream>>>(rows, cols, vals, bufA, bufB);
        acc_zero_kernel<<<ew_blocks, 256, 0, stream>>>(out, bufB, bufA);
        spmm_kernel<<<spmmA_blocks, 256, 0, stream>>>(rows, cols, vals, bufB, bufA);
        acc_zero_kernel<<<ew_blocks, 256, 0, stream>>>(out, bufA, bufB);
        spmm_kernel<<<spmmA_blocks, 256, 0, stream>>>(rows, cols, vals, bufA, bufB);
        final_kernel<<<ew_blocks, 256, 0, stream>>>(out, bufB);
    }
}